// Round 6
// baseline (105.466 us; speedup 1.0000x reference)
//
#include <hip/hip_runtime.h>
#include <hip/hip_bf16.h>

#define B_SZ 256
#define L_SZ 50
#define N_SZ 100000
#define D_SZ 128
#define NBT ((N_SZ + 63) / 64)   // 1563 col-tiles of 64
#define NSTREAM 512              // col streams; block g: stream g>>1, row-half g&1

typedef __attribute__((ext_vector_type(8))) short bf16x8;
typedef __attribute__((ext_vector_type(4))) float f32x4;

__device__ inline unsigned short f2bf(float f) {
    union { float f; unsigned u; } v; v.f = f;
    unsigned r = v.u + 0x7FFFu + ((v.u >> 16) & 1u);   // round-to-nearest-even
    return (unsigned short)(r >> 16);
}

// ---------------- kernel 1: per-b, gather v, qW1/qW2, att, u -> bf16 (512 thr)
__global__ __launch_bounds__(512) void k_ub(const int* __restrict__ seeds,
                                            const float* __restrict__ E,
                                            const float* __restrict__ pe,
                                            const float* __restrict__ W1,
                                            const float* __restrict__ W2,
                                            const float* __restrict__ q,
                                            const float* __restrict__ b_att,
                                            unsigned short* __restrict__ u_bf,
                                            float* __restrict__ loss_slot) {
    __shared__ float vbuf[L_SZ][D_SZ + 1];
    __shared__ int   sseed[L_SZ];
    __shared__ float qs[D_SZ], qw1s[D_SZ], qw2s[D_SZ];
    __shared__ float part1[4][D_SZ], part2[4][D_SZ];
    __shared__ float att[L_SZ];
    __shared__ float c2s, qsums;
    int b = blockIdx.x, t = threadIdx.x;
    int g = t >> 7, d = t & 127;             // 4 groups x 128 threads

    if (t < L_SZ) sseed[t] = seeds[b * L_SZ + t];
    if (t < D_SZ) qs[t] = q[t];
    __syncthreads();

    // gather: group g handles rows l = g, g+4, ... (independent -> ILP)
    #pragma unroll 4
    for (int l = g; l < L_SZ; l += 4)
        vbuf[l][d] = E[(size_t)sseed[l] * D_SZ + d] + pe[l * D_SZ + d];

    // qW1/qW2: group g sums e in [g*32, g*32+32)
    {
        float a1 = 0.f, a2 = 0.f;
        int e0 = g * 32;
        #pragma unroll 8
        for (int e = e0; e < e0 + 32; ++e) {
            float qe = qs[e];
            a1 += qe * W1[e * D_SZ + d];
            a2 += qe * W2[e * D_SZ + d];
        }
        part1[g][d] = a1;
        part2[g][d] = a2;
    }
    __syncthreads();
    if (t < D_SZ) {
        qw1s[t] = part1[0][t] + part1[1][t] + part1[2][t] + part1[3][t];
        qw2s[t] = part2[0][t] + part2[1][t] + part2[2][t] + part2[3][t];
    }
    __syncthreads();

    // att[l] = vbuf[l,:] . qw1  — 8 lanes per row, shuffle-reduce (width 8)
    if (t < L_SZ * 8) {
        int l = t >> 3, sub = t & 7;
        float p = 0.f;
        #pragma unroll
        for (int k = sub * 16; k < sub * 16 + 16; ++k) p += vbuf[l][k] * qw1s[k];
        p += __shfl_xor(p, 1, 8);
        p += __shfl_xor(p, 2, 8);
        p += __shfl_xor(p, 4, 8);
        if (sub == 0) att[l] = p;
    } else if (t < L_SZ * 8 + 8) {           // c2 = vn . qw2
        int sub = t & 7;
        float p = 0.f;
        #pragma unroll
        for (int k = sub * 16; k < sub * 16 + 16; ++k) p += vbuf[L_SZ - 1][k] * qw2s[k];
        p += __shfl_xor(p, 1, 8);
        p += __shfl_xor(p, 2, 8);
        p += __shfl_xor(p, 4, 8);
        if (sub == 0) c2s = p;
    } else if (t < L_SZ * 8 + 16) {          // qsum
        int sub = t & 7;
        float p = 0.f;
        #pragma unroll
        for (int k = sub * 16; k < sub * 16 + 16; ++k) p += qs[k];
        p += __shfl_xor(p, 1, 8);
        p += __shfl_xor(p, 2, 8);
        p += __shfl_xor(p, 4, 8);
        if (sub == 0) qsums = p;
    }
    __syncthreads();

    // u[d] = sum_l (att[l]+add) * vbuf[l][d], l split over 4 groups
    float add = c2s + b_att[0] * qsums;
    float up = 0.f;
    #pragma unroll 4
    for (int l = g; l < L_SZ; l += 4) up += (att[l] + add) * vbuf[l][d];
    __syncthreads();                          // part1 free for reuse
    part1[g][d] = up;
    __syncthreads();
    if (t < D_SZ)
        u_bf[b * D_SZ + t] = f2bf(part1[0][t] + part1[1][t] + part1[2][t] + part1[3][t]);

    if (b == 0 && t == 0) loss_slot[0] = 0.f;
}

// ---------------- kernel 2: scores = u @ E^T + bias (bf16 MFMA, multi-tile blocks)
// grid 1024: stream s = g>>1 (col-tiles s, s+512, ...), hf = g&1 (rows hf*128..+128).
// u-half (32 KB) staged ONCE per block, XOR-swizzled; then loop col-tiles:
// E frags -> MFMA -> f32x4 stores spread across the loop. 4 blocks/CU.
__global__ __launch_bounds__(256, 4) void k_gemm(const float* __restrict__ E,
                                                 const float* __restrict__ out_bias,
                                                 const unsigned short* __restrict__ u_bf,
                                                 float* __restrict__ scores,
                                                 float* __restrict__ partial) {
    __shared__ unsigned short us[128 * D_SZ];    // 32 KB swizzled u-half
    __shared__ float lds_sum[128];
    int tid = threadIdx.x;
    int w = tid >> 6, lane = tid & 63;
    int s = blockIdx.x >> 1, hf = blockIdx.x & 1;
    if (tid < 128) lds_sum[tid] = 0.f;

    // ---- stage u-half once: coalesced reads, swizzled writes (byte ^= (row&7)<<4)
    const char* ub = (const char*)u_bf + hf * 32768;
    #pragma unroll
    for (int r = 0; r < 8; ++r) {
        int off = r * 4096 + tid * 16;
        int brow = off >> 8, inrow = off & 255;
        bf16x8 v = *(const bf16x8*)(ub + off);
        *(bf16x8*)((char*)us + brow * 256 + (inrow ^ ((brow & 7) << 4))) = v;
    }

    int lo = lane & 15, hi = lane >> 4;
    int kb = hi * 8;
    __syncthreads();                             // u staged; lds_sum zeroed

    for (int ct = s; ct < NBT; ct += NSTREAM) {
        int nc = ct * 64 + w * 16;               // this wave's 16-col panel
        bool valid = (nc < N_SZ);                // wave-uniform (N_SZ % 16 == 0)

        // E frags: rows nc+lo, f32 -> bf16
        long erow = valid ? (nc + lo) : 0;
        bf16x8 efrag[4];
        #pragma unroll
        for (int ks = 0; ks < 4; ++ks) {
            const float* p = E + (size_t)erow * D_SZ + ks * 32 + kb;
            float4 x = *(const float4*)p;
            float4 y = *(const float4*)(p + 4);
            bf16x8 f;
            f[0] = (short)f2bf(x.x); f[1] = (short)f2bf(x.y);
            f[2] = (short)f2bf(x.z); f[3] = (short)f2bf(x.w);
            f[4] = (short)f2bf(y.x); f[5] = (short)f2bf(y.y);
            f[6] = (short)f2bf(y.z); f[7] = (short)f2bf(y.w);
            efrag[ks] = f;
        }
        int nb = valid ? (nc + hi * 4) : 0;      // this lane's 4 consecutive n
        float4 bias4 = *(const float4*)(out_bias + nb);

        #pragma unroll
        for (int rs = 0; rs < 8; ++rs) {
            f32x4 acc = (f32x4){0.f, 0.f, 0.f, 0.f};
            #pragma unroll
            for (int ks = 0; ks < 4; ++ks) {
                int brow = rs * 16 + lo;
                int kcol = ks * 64 + hi * 16;
                bf16x8 uf = *(const bf16x8*)((const char*)us + brow * 256 + (kcol ^ ((brow & 7) << 4)));
                acc = __builtin_amdgcn_mfma_f32_16x16x32_bf16(efrag[ks], uf, acc, 0, 0, 0);
            }
            int jl = rs * 16 + lo;               // local b-row
            int jr = hf * 128 + jl;              // global b-row
            f32x4 c;
            c[0] = acc[0] + bias4.x;
            c[1] = acc[1] + bias4.y;
            c[2] = acc[2] + bias4.z;
            c[3] = acc[3] + bias4.w;
            if (valid) {
                *(f32x4*)(scores + (size_t)jr * N_SZ + nb) = c;
                float p = __expf(c[0]) + __expf(c[1]) + __expf(c[2]) + __expf(c[3]);
                p += __shfl_xor(p, 16);
                p += __shfl_xor(p, 32);          // lanes {l, l^16, l^32, l^48} share jl
                if (hi == 0) atomicAdd(&lds_sum[jl], p);
            }
        }
    }
    __syncthreads();
    if (tid < 128) partial[(size_t)blockIdx.x * 128 + tid] = lds_sum[tid];
}

// ---------------- kernel 3: per-row logsumexp + NLL mean
__global__ __launch_bounds__(256) void k_loss(const float* __restrict__ partial,
                                              const float* __restrict__ scores,
                                              const int* __restrict__ labels,
                                              float* __restrict__ out_loss) {
    int b = blockIdx.x, t = threadIdx.x;
    int hf = b >> 7, r = b & 127;
    float acc = 0.f;
    for (int i = t; i < NSTREAM; i += 256) acc += partial[(size_t)(i * 2 + hf) * 128 + r];
    __shared__ float red[256];
    red[t] = acc;
    __syncthreads();
    for (int st = 128; st > 0; st >>= 1) {
        if (t < st) red[t] += red[t + st];
        __syncthreads();
    }
    if (t == 0) {
        int lab = labels[b];
        float val = scores[(size_t)b * N_SZ + lab] - logf(red[0]);
        atomicAdd(out_loss, -val * (1.0f / (float)B_SZ));
    }
}

extern "C" void kernel_launch(void* const* d_in, const int* in_sizes, int n_in,
                              void* d_out, int out_size, void* d_ws, size_t ws_size,
                              hipStream_t stream) {
    const int*   seeds    = (const int*)d_in[0];
    const int*   labels   = (const int*)d_in[1];
    const float* E        = (const float*)d_in[2];
    const float* W1       = (const float*)d_in[3];
    const float* W2       = (const float*)d_in[4];
    const float* q        = (const float*)d_in[5];
    const float* b_att    = (const float*)d_in[6];
    const float* out_bias = (const float*)d_in[7];
    const float* pe       = (const float*)d_in[8];

    float* scores = (float*)d_out;
    float* loss   = scores + (size_t)B_SZ * N_SZ;

    // ws layout: @2048 u_bf16 (64KB) | @67584 partial (1024*128*4 = 512KB)
    unsigned short* u_bf    = (unsigned short*)((char*)d_ws + 2048);
    float*          partial = (float*)((char*)d_ws + 67584);

    k_ub<<<B_SZ, 512, 0, stream>>>(seeds, E, pe, W1, W2, q, b_att, u_bf, loss);
    k_gemm<<<NSTREAM * 2, 256, 0, stream>>>(E, out_bias, u_bf, scores, partial);
    k_loss<<<B_SZ, 256, 0, stream>>>(partial, scores, labels, loss);
}

// Round 7
// 57.436 us; speedup vs baseline: 1.8363x; 1.8363x over previous
//
#include <hip/hip_runtime.h>
#include <hip/hip_bf16.h>

#define B_SZ 256
#define L_SZ 50
#define N_SZ 100000
#define D_SZ 128
#define NB ((N_SZ + 127) / 128)   // 782 col-tiles of 128

typedef __attribute__((ext_vector_type(8))) short bf16x8;
typedef __attribute__((ext_vector_type(4))) float f32x4;

__device__ inline unsigned short f2bf(float f) {
    union { float f; unsigned u; } v; v.f = f;
    unsigned r = v.u + 0x7FFFu + ((v.u >> 16) & 1u);   // round-to-nearest-even
    return (unsigned short)(r >> 16);
}

// ---------------- kernel 1: per-b, gather v, qW1/qW2, att, u -> bf16 (512 thr, fused prep)
__global__ __launch_bounds__(512) void k_ub(const int* __restrict__ seeds,
                                            const float* __restrict__ E,
                                            const float* __restrict__ pe,
                                            const float* __restrict__ W1,
                                            const float* __restrict__ W2,
                                            const float* __restrict__ q,
                                            const float* __restrict__ b_att,
                                            unsigned short* __restrict__ u_bf,
                                            float* __restrict__ loss_slot) {
    __shared__ float vbuf[L_SZ][D_SZ + 1];
    __shared__ int   sseed[L_SZ];
    __shared__ float qs[D_SZ], qw1s[D_SZ], qw2s[D_SZ];
    __shared__ float part1[4][D_SZ], part2[4][D_SZ];
    __shared__ float att[L_SZ];
    __shared__ float c2s, qsums;
    int b = blockIdx.x, t = threadIdx.x;
    int g = t >> 7, d = t & 127;             // 4 groups x 128 threads

    if (t < L_SZ) sseed[t] = seeds[b * L_SZ + t];
    if (t < D_SZ) qs[t] = q[t];
    __syncthreads();

    // gather: group g handles rows l = g, g+4, ... (independent -> ILP)
    #pragma unroll 4
    for (int l = g; l < L_SZ; l += 4)
        vbuf[l][d] = E[(size_t)sseed[l] * D_SZ + d] + pe[l * D_SZ + d];

    // qW1/qW2: group g sums e in [g*32, g*32+32)
    {
        float a1 = 0.f, a2 = 0.f;
        int e0 = g * 32;
        #pragma unroll 8
        for (int e = e0; e < e0 + 32; ++e) {
            float qe = qs[e];
            a1 += qe * W1[e * D_SZ + d];
            a2 += qe * W2[e * D_SZ + d];
        }
        part1[g][d] = a1;
        part2[g][d] = a2;
    }
    __syncthreads();
    if (t < D_SZ) {
        qw1s[t] = part1[0][t] + part1[1][t] + part1[2][t] + part1[3][t];
        qw2s[t] = part2[0][t] + part2[1][t] + part2[2][t] + part2[3][t];
    }
    __syncthreads();

    // att[l] = vbuf[l,:] . qw1  — 8 lanes per row, shuffle-reduce (width 8)
    if (t < L_SZ * 8) {
        int l = t >> 3, sub = t & 7;
        float p = 0.f;
        #pragma unroll
        for (int k = sub * 16; k < sub * 16 + 16; ++k) p += vbuf[l][k] * qw1s[k];
        p += __shfl_xor(p, 1, 8);
        p += __shfl_xor(p, 2, 8);
        p += __shfl_xor(p, 4, 8);
        if (sub == 0) att[l] = p;
    } else if (t < L_SZ * 8 + 8) {           // c2 = vn . qw2
        int sub = t & 7;
        float p = 0.f;
        #pragma unroll
        for (int k = sub * 16; k < sub * 16 + 16; ++k) p += vbuf[L_SZ - 1][k] * qw2s[k];
        p += __shfl_xor(p, 1, 8);
        p += __shfl_xor(p, 2, 8);
        p += __shfl_xor(p, 4, 8);
        if (sub == 0) c2s = p;
    } else if (t < L_SZ * 8 + 16) {          // qsum
        int sub = t & 7;
        float p = 0.f;
        #pragma unroll
        for (int k = sub * 16; k < sub * 16 + 16; ++k) p += qs[k];
        p += __shfl_xor(p, 1, 8);
        p += __shfl_xor(p, 2, 8);
        p += __shfl_xor(p, 4, 8);
        if (sub == 0) qsums = p;
    }
    __syncthreads();

    // u[d] = sum_l (att[l]+add) * vbuf[l][d], l split over 4 groups
    float add = c2s + b_att[0] * qsums;
    float up = 0.f;
    #pragma unroll 4
    for (int l = g; l < L_SZ; l += 4) up += (att[l] + add) * vbuf[l][d];
    __syncthreads();                          // part1 free for reuse
    part1[g][d] = up;
    __syncthreads();
    if (t < D_SZ)
        u_bf[b * D_SZ + t] = f2bf(part1[0][t] + part1[1][t] + part1[2][t] + part1[3][t]);

    if (b == 0 && t == 0) loss_slot[0] = 0.f;
}

// ---------------- kernel 2: scores = u @ E^T + bias (bf16 MFMA)  [R4 structure]
// 512 threads = 8 waves; block covers 128 n-cols x ALL 256 b-rows. u (64 KB)
// staged in LDS, XOR-swizzled (byte ^= (b&7)<<4) for conflict-free ds_read_b128.
// E read exactly once per launch, blocks in dispatch order (L2/L3-friendly).
// D layout: row=(lane>>4)*4+g -> n, col=lane&15 -> b => 16B stores per lane.
__global__ __launch_bounds__(512, 4) void k_gemm(const float* __restrict__ E,
                                                 const float* __restrict__ out_bias,
                                                 const unsigned short* __restrict__ u_bf,
                                                 float* __restrict__ scores,
                                                 float* __restrict__ partial) {
    __shared__ unsigned short us[B_SZ * D_SZ];   // 64 KB swizzled u
    __shared__ float lds_sum[B_SZ];
    int tid = threadIdx.x;
    int w = tid >> 6, lane = tid & 63;
    if (tid < B_SZ) lds_sum[tid] = 0.f;

    // ---- stage u: coalesced 16B/thread global reads, swizzled LDS writes
    #pragma unroll
    for (int r = 0; r < 8; ++r) {
        int off = r * 8192 + tid * 16;           // flat byte offset into u_bf
        int brow = off >> 8, inrow = off & 255;
        bf16x8 v = *(const bf16x8*)((const char*)u_bf + off);
        *(bf16x8*)((char*)us + brow * 256 + (inrow ^ ((brow & 7) << 4))) = v;
    }

    int nc = blockIdx.x * 128 + w * 16;          // this wave's 16-col panel
    bool valid = (nc < N_SZ);                    // wave-uniform (N_SZ % 16 == 0)
    int lo = lane & 15, hi = lane >> 4;
    int kb = hi * 8;

    // ---- A fragments: E rows (= score cols), f32 -> bf16 in regs
    long erow = valid ? (nc + lo) : 0;
    bf16x8 efrag[4];
    #pragma unroll
    for (int ks = 0; ks < 4; ++ks) {
        const float* p = E + (size_t)erow * D_SZ + ks * 32 + kb;
        float4 x = *(const float4*)p;
        float4 y = *(const float4*)(p + 4);
        bf16x8 f;
        f[0] = (short)f2bf(x.x); f[1] = (short)f2bf(x.y);
        f[2] = (short)f2bf(x.z); f[3] = (short)f2bf(x.w);
        f[4] = (short)f2bf(y.x); f[5] = (short)f2bf(y.y);
        f[6] = (short)f2bf(y.z); f[7] = (short)f2bf(y.w);
        efrag[ks] = f;
    }
    int nb = valid ? (nc + hi * 4) : 0;          // this lane's 4 consecutive n
    float4 bias4 = *(const float4*)(out_bias + nb);

    __syncthreads();                             // u staged; lds_sum zeroed

    // ---- 16 persistent accumulators; ks-outer: 16 independent ds_reads+MFMAs
    f32x4 acc[16];
    #pragma unroll
    for (int i = 0; i < 16; ++i) acc[i] = (f32x4){0.f, 0.f, 0.f, 0.f};

    #pragma unroll
    for (int ks = 0; ks < 4; ++ks) {
        int kcol = ks * 64 + hi * 16;            // byte offset of 16B k-chunk
        #pragma unroll
        for (int rs = 0; rs < 16; ++rs) {
            int brow = rs * 16 + lo;
            bf16x8 uf = *(const bf16x8*)((const char*)us + brow * 256 + (kcol ^ ((brow & 7) << 4)));
            acc[rs] = __builtin_amdgcn_mfma_f32_16x16x32_bf16(efrag[ks], uf, acc[rs], 0, 0, 0);
        }
    }

    #pragma unroll
    for (int rs = 0; rs < 16; ++rs) {
        int jr = rs * 16 + lo;                   // this lane's b-row
        f32x4 c;
        c[0] = acc[rs][0] + bias4.x;
        c[1] = acc[rs][1] + bias4.y;
        c[2] = acc[rs][2] + bias4.z;
        c[3] = acc[rs][3] + bias4.w;
        if (valid)
            *(f32x4*)(scores + (size_t)jr * N_SZ + nb) = c;
        float p = __expf(c[0]) + __expf(c[1]) + __expf(c[2]) + __expf(c[3]);
        p += __shfl_xor(p, 16);
        p += __shfl_xor(p, 32);                  // lanes {l, l^16, l^32, l^48} share jr
        if (valid && hi == 0) atomicAdd(&lds_sum[jr], p);
    }
    __syncthreads();
    if (tid < B_SZ) partial[(size_t)blockIdx.x * B_SZ + tid] = lds_sum[tid];
}

// ---------------- kernel 3: per-row logsumexp + NLL mean
__global__ __launch_bounds__(256) void k_loss(const float* __restrict__ partial,
                                              const float* __restrict__ scores,
                                              const int* __restrict__ labels,
                                              float* __restrict__ out_loss) {
    int b = blockIdx.x, t = threadIdx.x;
    float acc = 0.f;
    for (int i = t; i < NB; i += 256) acc += partial[(size_t)i * B_SZ + b];
    __shared__ float red[256];
    red[t] = acc;
    __syncthreads();
    for (int s = 128; s > 0; s >>= 1) {
        if (t < s) red[t] += red[t + s];
        __syncthreads();
    }
    if (t == 0) {
        int lab = labels[b];
        float val = scores[(size_t)b * N_SZ + lab] - logf(red[0]);
        atomicAdd(out_loss, -val * (1.0f / (float)B_SZ));
    }
}

extern "C" void kernel_launch(void* const* d_in, const int* in_sizes, int n_in,
                              void* d_out, int out_size, void* d_ws, size_t ws_size,
                              hipStream_t stream) {
    const int*   seeds    = (const int*)d_in[0];
    const int*   labels   = (const int*)d_in[1];
    const float* E        = (const float*)d_in[2];
    const float* W1       = (const float*)d_in[3];
    const float* W2       = (const float*)d_in[4];
    const float* q        = (const float*)d_in[5];
    const float* b_att    = (const float*)d_in[6];
    const float* out_bias = (const float*)d_in[7];
    const float* pe       = (const float*)d_in[8];

    float* scores = (float*)d_out;
    float* loss   = scores + (size_t)B_SZ * N_SZ;

    // ws layout: @2048 u_bf16 (64KB) | @67584 partial (782*256*4 = 800KB)
    unsigned short* u_bf    = (unsigned short*)((char*)d_ws + 2048);
    float*          partial = (float*)((char*)d_ws + 67584);

    k_ub<<<B_SZ, 512, 0, stream>>>(seeds, E, pe, W1, W2, q, b_att, u_bf, loss);
    k_gemm<<<NB, 512, 0, stream>>>(E, out_bias, u_bf, scores, partial);
    k_loss<<<B_SZ, 256, 0, stream>>>(partial, scores, labels, loss);
}

// Round 8
// 57.230 us; speedup vs baseline: 1.8429x; 1.0036x over previous
//
#include <hip/hip_runtime.h>
#include <hip/hip_bf16.h>

#define B_SZ 256
#define L_SZ 50
#define N_SZ 100000
#define D_SZ 128
#define NB ((N_SZ + 127) / 128)   // 782 col-tiles of 128

typedef __attribute__((ext_vector_type(8))) short bf16x8;
typedef __attribute__((ext_vector_type(4))) float f32x4;

__device__ inline unsigned short f2bf(float f) {
    union { float f; unsigned u; } v; v.f = f;
    unsigned r = v.u + 0x7FFFu + ((v.u >> 16) & 1u);   // round-to-nearest-even
    return (unsigned short)(r >> 16);
}

// ---------------- kernel 1: per-b, gather v, qW1/qW2, att, u -> bf16 (512 thr, fused prep)
__global__ __launch_bounds__(512) void k_ub(const int* __restrict__ seeds,
                                            const float* __restrict__ E,
                                            const float* __restrict__ pe,
                                            const float* __restrict__ W1,
                                            const float* __restrict__ W2,
                                            const float* __restrict__ q,
                                            const float* __restrict__ b_att,
                                            unsigned short* __restrict__ u_bf,
                                            float* __restrict__ loss_slot) {
    __shared__ float vbuf[L_SZ][D_SZ + 1];
    __shared__ int   sseed[L_SZ];
    __shared__ float qs[D_SZ], qw1s[D_SZ], qw2s[D_SZ];
    __shared__ float part1[4][D_SZ], part2[4][D_SZ];
    __shared__ float att[L_SZ];
    __shared__ float c2s, qsums;
    int b = blockIdx.x, t = threadIdx.x;
    int g = t >> 7, d = t & 127;             // 4 groups x 128 threads

    if (t < L_SZ) sseed[t] = seeds[b * L_SZ + t];
    if (t < D_SZ) qs[t] = q[t];
    __syncthreads();

    // gather: group g handles rows l = g, g+4, ... (independent -> ILP)
    #pragma unroll 4
    for (int l = g; l < L_SZ; l += 4)
        vbuf[l][d] = E[(size_t)sseed[l] * D_SZ + d] + pe[l * D_SZ + d];

    // qW1/qW2: group g sums e in [g*32, g*32+32)
    {
        float a1 = 0.f, a2 = 0.f;
        int e0 = g * 32;
        #pragma unroll 8
        for (int e = e0; e < e0 + 32; ++e) {
            float qe = qs[e];
            a1 += qe * W1[e * D_SZ + d];
            a2 += qe * W2[e * D_SZ + d];
        }
        part1[g][d] = a1;
        part2[g][d] = a2;
    }
    __syncthreads();
    if (t < D_SZ) {
        qw1s[t] = part1[0][t] + part1[1][t] + part1[2][t] + part1[3][t];
        qw2s[t] = part2[0][t] + part2[1][t] + part2[2][t] + part2[3][t];
    }
    __syncthreads();

    // att[l] = vbuf[l,:] . qw1  — 8 lanes per row, shuffle-reduce (width 8)
    if (t < L_SZ * 8) {
        int l = t >> 3, sub = t & 7;
        float p = 0.f;
        #pragma unroll
        for (int k = sub * 16; k < sub * 16 + 16; ++k) p += vbuf[l][k] * qw1s[k];
        p += __shfl_xor(p, 1, 8);
        p += __shfl_xor(p, 2, 8);
        p += __shfl_xor(p, 4, 8);
        if (sub == 0) att[l] = p;
    } else if (t < L_SZ * 8 + 8) {           // c2 = vn . qw2
        int sub = t & 7;
        float p = 0.f;
        #pragma unroll
        for (int k = sub * 16; k < sub * 16 + 16; ++k) p += vbuf[L_SZ - 1][k] * qw2s[k];
        p += __shfl_xor(p, 1, 8);
        p += __shfl_xor(p, 2, 8);
        p += __shfl_xor(p, 4, 8);
        if (sub == 0) c2s = p;
    } else if (t < L_SZ * 8 + 16) {          // qsum
        int sub = t & 7;
        float p = 0.f;
        #pragma unroll
        for (int k = sub * 16; k < sub * 16 + 16; ++k) p += qs[k];
        p += __shfl_xor(p, 1, 8);
        p += __shfl_xor(p, 2, 8);
        p += __shfl_xor(p, 4, 8);
        if (sub == 0) qsums = p;
    }
    __syncthreads();

    // u[d] = sum_l (att[l]+add) * vbuf[l][d], l split over 4 groups
    float add = c2s + b_att[0] * qsums;
    float up = 0.f;
    #pragma unroll 4
    for (int l = g; l < L_SZ; l += 4) up += (att[l] + add) * vbuf[l][d];
    __syncthreads();                          // part1 free for reuse
    part1[g][d] = up;
    __syncthreads();
    if (t < D_SZ)
        u_bf[b * D_SZ + t] = f2bf(part1[0][t] + part1[1][t] + part1[2][t] + part1[3][t]);

    if (b == 0 && t == 0) loss_slot[0] = 0.f;
}

// ---------------- kernel 2: scores = u @ E^T + bias (bf16 MFMA)
// R4 structure (512 thr, 128 n-cols x 256 b-rows, full-u 64 KB swizzled LDS),
// but the epilogue is interleaved: 4 groups of 4 rs, each group's stores+exp
// issued right after its MFMAs -> the 102 MB write stream is spread across
// the kernel instead of a terminal burst. sched_barrier pins the grouping.
__global__ __launch_bounds__(512, 4) void k_gemm(const float* __restrict__ E,
                                                 const float* __restrict__ out_bias,
                                                 const unsigned short* __restrict__ u_bf,
                                                 float* __restrict__ scores,
                                                 float* __restrict__ partial) {
    __shared__ unsigned short us[B_SZ * D_SZ];   // 64 KB swizzled u
    __shared__ float lds_sum[B_SZ];
    int tid = threadIdx.x;
    int w = tid >> 6, lane = tid & 63;
    if (tid < B_SZ) lds_sum[tid] = 0.f;

    // ---- stage u: coalesced 16B/thread global reads, swizzled LDS writes
    #pragma unroll
    for (int r = 0; r < 8; ++r) {
        int off = r * 8192 + tid * 16;           // flat byte offset into u_bf
        int brow = off >> 8, inrow = off & 255;
        bf16x8 v = *(const bf16x8*)((const char*)u_bf + off);
        *(bf16x8*)((char*)us + brow * 256 + (inrow ^ ((brow & 7) << 4))) = v;
    }

    int nc = blockIdx.x * 128 + w * 16;          // this wave's 16-col panel
    bool valid = (nc < N_SZ);                    // wave-uniform (N_SZ % 16 == 0)
    int lo = lane & 15, hi = lane >> 4;
    int kb = hi * 8;

    // ---- A fragments: E rows (= score cols), f32 -> bf16 in regs
    long erow = valid ? (nc + lo) : 0;
    bf16x8 efrag[4];
    #pragma unroll
    for (int ks = 0; ks < 4; ++ks) {
        const float* p = E + (size_t)erow * D_SZ + ks * 32 + kb;
        float4 x = *(const float4*)p;
        float4 y = *(const float4*)(p + 4);
        bf16x8 f;
        f[0] = (short)f2bf(x.x); f[1] = (short)f2bf(x.y);
        f[2] = (short)f2bf(x.z); f[3] = (short)f2bf(x.w);
        f[4] = (short)f2bf(y.x); f[5] = (short)f2bf(y.y);
        f[6] = (short)f2bf(y.z); f[7] = (short)f2bf(y.w);
        efrag[ks] = f;
    }
    int nb = valid ? (nc + hi * 4) : 0;          // this lane's 4 consecutive n
    float4 bias4 = *(const float4*)(out_bias + nb);

    __syncthreads();                             // u staged; lds_sum zeroed

    // ---- 4 groups of 4 rs: MFMA (ks-outer, ILP=4) then store+exp immediately
    #pragma unroll
    for (int grp = 0; grp < 4; ++grp) {
        f32x4 acc[4];
        #pragma unroll
        for (int i = 0; i < 4; ++i) acc[i] = (f32x4){0.f, 0.f, 0.f, 0.f};

        #pragma unroll
        for (int ks = 0; ks < 4; ++ks) {
            int kcol = ks * 64 + hi * 16;        // byte offset of 16B k-chunk
            #pragma unroll
            for (int r4 = 0; r4 < 4; ++r4) {
                int brow = (grp * 4 + r4) * 16 + lo;
                bf16x8 uf = *(const bf16x8*)((const char*)us + brow * 256 + (kcol ^ ((brow & 7) << 4)));
                acc[r4] = __builtin_amdgcn_mfma_f32_16x16x32_bf16(efrag[ks], uf, acc[r4], 0, 0, 0);
            }
        }

        #pragma unroll
        for (int r4 = 0; r4 < 4; ++r4) {
            int jr = (grp * 4 + r4) * 16 + lo;   // this lane's b-row
            f32x4 c;
            c[0] = acc[r4][0] + bias4.x;
            c[1] = acc[r4][1] + bias4.y;
            c[2] = acc[r4][2] + bias4.z;
            c[3] = acc[r4][3] + bias4.w;
            if (valid)
                *(f32x4*)(scores + (size_t)jr * N_SZ + nb) = c;
            float p = __expf(c[0]) + __expf(c[1]) + __expf(c[2]) + __expf(c[3]);
            p += __shfl_xor(p, 16);
            p += __shfl_xor(p, 32);              // lanes {l, l^16, l^32, l^48} share jr
            if (valid && hi == 0) atomicAdd(&lds_sum[jr], p);
        }
        __builtin_amdgcn_sched_barrier(0);       // keep stores inside their group
    }
    __syncthreads();
    if (tid < B_SZ) partial[(size_t)blockIdx.x * B_SZ + tid] = lds_sum[tid];
}

// ---------------- kernel 3: per-row logsumexp + NLL mean
__global__ __launch_bounds__(256) void k_loss(const float* __restrict__ partial,
                                              const float* __restrict__ scores,
                                              const int* __restrict__ labels,
                                              float* __restrict__ out_loss) {
    int b = blockIdx.x, t = threadIdx.x;
    float acc = 0.f;
    for (int i = t; i < NB; i += 256) acc += partial[(size_t)i * B_SZ + b];
    __shared__ float red[256];
    red[t] = acc;
    __syncthreads();
    for (int s = 128; s > 0; s >>= 1) {
        if (t < s) red[t] += red[t + s];
        __syncthreads();
    }
    if (t == 0) {
        int lab = labels[b];
        float val = scores[(size_t)b * N_SZ + lab] - logf(red[0]);
        atomicAdd(out_loss, -val * (1.0f / (float)B_SZ));
    }
}

extern "C" void kernel_launch(void* const* d_in, const int* in_sizes, int n_in,
                              void* d_out, int out_size, void* d_ws, size_t ws_size,
                              hipStream_t stream) {
    const int*   seeds    = (const int*)d_in[0];
    const int*   labels   = (const int*)d_in[1];
    const float* E        = (const float*)d_in[2];
    const float* W1       = (const float*)d_in[3];
    const float* W2       = (const float*)d_in[4];
    const float* q        = (const float*)d_in[5];
    const float* b_att    = (const float*)d_in[6];
    const float* out_bias = (const float*)d_in[7];
    const float* pe       = (const float*)d_in[8];

    float* scores = (float*)d_out;
    float* loss   = scores + (size_t)B_SZ * N_SZ;

    // ws layout: @2048 u_bf16 (64KB) | @67584 partial (782*256*4 = 800KB)
    unsigned short* u_bf    = (unsigned short*)((char*)d_ws + 2048);
    float*          partial = (float*)((char*)d_ws + 67584);

    k_ub<<<B_SZ, 512, 0, stream>>>(seeds, E, pe, W1, W2, q, b_att, u_bf, loss);
    k_gemm<<<NB, 512, 0, stream>>>(E, out_bias, u_bf, scores, partial);
    k_loss<<<B_SZ, 256, 0, stream>>>(partial, scores, labels, loss);
}